// Round 7
// baseline (18529.608 us; speedup 1.0000x reference)
//
#include <hip/hip_runtime.h>
#include <hip/hip_bf16.h>
#include <hip/hip_fp16.h>

#define B_ 64
#define T_ 1024
#define I_ 256
#define H_ 512
#define O_ 256
#define S_ 4        // k-split factor

typedef _Float16 h2v __attribute__((ext_vector_type(2)));
union U16x4 { uint4 u; h2v h[4]; _Float16 f[8]; };

// ---------------------------------------------------------------- K0: pack W_hh -> fp16 chunks
// chunk c = q*512 + j holds W[8q+0..8q+7][j] as 8 halfs (16B). q = k/8.
__global__ __launch_bounds__(256) void k_pack_whh(const float* __restrict__ whh, uint4* __restrict__ out) {
    int c = blockIdx.x * 256 + threadIdx.x;      // 0 .. 64*512-1
    int q = c >> 9;
    int j = c & 511;
    U16x4 r;
    #pragma unroll
    for (int i = 0; i < 8; ++i)
        r.f[i] = (_Float16)whh[(size_t)(q * 8 + i) * H_ + j];
    out[c] = r.u;
}

// ---------------------------------------------------------------- K1: xW = x @ W_xh + b_h   [65536,256]@[256,512]
__global__ __launch_bounds__(256) void k_xw(const float* __restrict__ A,
                                            const float* __restrict__ Bw,
                                            const float* __restrict__ bias,
                                            float* __restrict__ C) {
    __shared__ float As[16][64 + 4];
    __shared__ float Bs[16][64 + 4];
    const int tid = threadIdx.x;
    const int tx = tid & 15, ty = tid >> 4;
    const int bm = blockIdx.y * 64;
    const int bn = blockIdx.x * 64;
    float acc[4][4] = {};

    for (int k0 = 0; k0 < I_; k0 += 16) {
        {
            int r = tid >> 2, kq = (tid & 3) * 4;
            float4 v = *reinterpret_cast<const float4*>(&A[(size_t)(bm + r) * I_ + k0 + kq]);
            As[kq + 0][r] = v.x; As[kq + 1][r] = v.y; As[kq + 2][r] = v.z; As[kq + 3][r] = v.w;
        }
        {
            int kr = tid >> 4, nq = (tid & 15) * 4;
            float4 v = *reinterpret_cast<const float4*>(&Bw[(size_t)(k0 + kr) * H_ + bn + nq]);
            *reinterpret_cast<float4*>(&Bs[kr][nq]) = v;
        }
        __syncthreads();
        #pragma unroll
        for (int kk = 0; kk < 16; ++kk) {
            float a[4], b[4];
            *reinterpret_cast<float4*>(a) = *reinterpret_cast<const float4*>(&As[kk][ty * 4]);
            *reinterpret_cast<float4*>(b) = *reinterpret_cast<const float4*>(&Bs[kk][tx * 4]);
            #pragma unroll
            for (int i = 0; i < 4; ++i)
                #pragma unroll
                for (int jx = 0; jx < 4; ++jx)
                    acc[i][jx] = fmaf(a[i], b[jx], acc[i][jx]);
        }
        __syncthreads();
    }
    #pragma unroll
    for (int i = 0; i < 4; ++i) {
        int r = bm + ty * 4 + i;
        float4 o;
        o.x = acc[i][0] + bias[bn + tx * 4 + 0];
        o.y = acc[i][1] + bias[bn + tx * 4 + 1];
        o.z = acc[i][2] + bias[bn + tx * 4 + 2];
        o.w = acc[i][3] + bias[bn + tx * 4 + 3];
        *reinterpret_cast<float4*>(&C[(size_t)r * H_ + bn + tx * 4]) = o;
    }
}

// ---------------------------------------------------------------- K2: persistent recurrence, 4-way k-split
// 256 blocks = 4 per batch row. W slice (128 k x own column) lives in 64 VGPRs.
// Per step: partial dot -> agent-scope store -> release atomicAdd on per-row counter ->
// relaxed poll + acquire fence -> read partners' partials -> redundant sum+tanh in all
// 4 blocks (h never needs a 2nd sync). h kept fp16 in LDS (broadcast reads).
__global__ __launch_bounds__(512, 4) void k_rnn(const uint4* __restrict__ Wp,   // [64][512] 16B chunks
                                                float* __restrict__ HA,         // [B,T,H] in: xw, out: h
                                                const float* __restrict__ h0,
                                                float* __restrict__ hT,
                                                float* __restrict__ part,       // [2][S][B][H] f32
                                                int* __restrict__ cnt) {        // [B*16], zeroed per launch
    __shared__ __align__(16) _Float16 hbuf[2][H_];   // 2 KB
    const int r = blockIdx.x & 63;                   // batch row
    const int s = blockIdx.x >> 6;                   // k-slice 0..3 (partners same XCD mod-8)
    const int j = threadIdx.x;                       // column 0..511

    // W slice -> 64 VGPRs: chunks q = s*16+u, column j  (W[s*128+8u .. +7][j])
    uint4 w[16];
    #pragma unroll
    for (int u = 0; u < 16; ++u)
        w[u] = Wp[(((size_t)(s * 16 + u)) << 9) + j];

    hbuf[0][j] = (_Float16)h0[((size_t)r << 9) + j];

    float* harow = HA + (((size_t)r * T_) << 9);
    int* myc = cnt + (r << 4);                       // 64B-strided counters
    const size_t rj = ((size_t)r << 9) + j;
    const size_t sstride = (size_t)B_ * H_;
    float* p0b = part + rj;                          // t even
    float* p1b = part + (size_t)S_ * sstride + rj;   // t odd
    int cur = 0;
    float hn = 0.f;
    __syncthreads();

    for (int t = 0; t < T_; ++t) {
        // xw load (block 0 only) issued early to overlap LDS+VALU
        float xw = 0.f;
        if (s == 0) xw = harow[((size_t)t << 9) + j];

        const uint4* hb = reinterpret_cast<const uint4*>(&hbuf[cur][0]) + (s << 4);
        float a0 = 0.f, a1 = 0.f, a2 = 0.f, a3 = 0.f;
        #pragma unroll
        for (int u = 0; u < 16; ++u) {
            U16x4 hh, ww;
            hh.u = hb[u];                            // uniform broadcast, conflict-free
            ww.u = w[u];
            a0 = __builtin_amdgcn_fdot2(ww.h[0], hh.h[0], a0, false);
            a1 = __builtin_amdgcn_fdot2(ww.h[1], hh.h[1], a1, false);
            a2 = __builtin_amdgcn_fdot2(ww.h[2], hh.h[2], a2, false);
            a3 = __builtin_amdgcn_fdot2(ww.h[3], hh.h[3], a3, false);
        }
        float acc = ((a0 + a1) + (a2 + a3)) + xw;

        float* pb = (t & 1) ? p1b : p0b;             // parity dbuf kills ABA race
        __hip_atomic_store(pb + (size_t)s * sstride, acc,
                           __ATOMIC_RELAXED, __HIP_MEMORY_SCOPE_AGENT);
        __syncthreads();                             // vmcnt drained before barrier -> stores done
        if (j == 0)
            __hip_atomic_fetch_add(myc, 1, __ATOMIC_RELEASE, __HIP_MEMORY_SCOPE_AGENT);
        const int target = (t + 1) << 2;             // S_*(t+1), monotonic counter
        while (__hip_atomic_load(myc, __ATOMIC_RELAXED, __HIP_MEMORY_SCOPE_AGENT) < target) {}
        __builtin_amdgcn_fence(__ATOMIC_ACQUIRE, "agent");

        float q[S_];
        #pragma unroll
        for (int ss = 0; ss < S_; ++ss)
            q[ss] = (ss == s) ? acc
                  : __hip_atomic_load(pb + (size_t)ss * sstride,
                                      __ATOMIC_RELAXED, __HIP_MEMORY_SCOPE_AGENT);
        hn = tanhf((q[0] + q[1]) + (q[2] + q[3]));

        if (s == 0) harow[((size_t)t << 9) + j] = hn;  // h_t for output GEMM (fp32)
        hbuf[cur ^ 1][j] = (_Float16)hn;               // local fp16 copy for next step
        __syncthreads();
        cur ^= 1;
    }
    if (s == 0) hT[rj] = hn;
}

// ---------------------------------------------------------------- K3: y = softmax(H @ W_hy + b_y)  fused
__global__ __launch_bounds__(256) void k_out(const float* __restrict__ Hh,   // [M,512]
                                             const float* __restrict__ Wy,   // [512,256]
                                             const float* __restrict__ by,   // [256]
                                             float* __restrict__ out) {      // [M,256]
    __shared__ float Hs[16][64 + 4];
    __shared__ float Ws[16][256];
    const int tid = threadIdx.x;
    const int tx = tid & 31, ty = tid >> 5;
    const int m0 = blockIdx.x * 64;
    float acc[8][8] = {};

    for (int k0 = 0; k0 < H_; k0 += 16) {
        {
            int r = tid >> 2, kq = (tid & 3) * 4;
            float4 v = *reinterpret_cast<const float4*>(&Hh[(size_t)(m0 + r) * H_ + k0 + kq]);
            Hs[kq + 0][r] = v.x; Hs[kq + 1][r] = v.y; Hs[kq + 2][r] = v.z; Hs[kq + 3][r] = v.w;
        }
        {
            int kr = tid >> 4, c0 = (tid & 15) * 16;
            const float4* src = reinterpret_cast<const float4*>(&Wy[(size_t)(k0 + kr) * O_ + c0]);
            float4* dst = reinterpret_cast<float4*>(&Ws[kr][c0]);
            dst[0] = src[0]; dst[1] = src[1]; dst[2] = src[2]; dst[3] = src[3];
        }
        __syncthreads();
        #pragma unroll
        for (int kk = 0; kk < 16; ++kk) {
            float a[8], bb[8];
            *reinterpret_cast<float4*>(&a[0])  = *reinterpret_cast<const float4*>(&Hs[kk][ty * 8]);
            *reinterpret_cast<float4*>(&a[4])  = *reinterpret_cast<const float4*>(&Hs[kk][ty * 8 + 4]);
            *reinterpret_cast<float4*>(&bb[0]) = *reinterpret_cast<const float4*>(&Ws[kk][tx * 8]);
            *reinterpret_cast<float4*>(&bb[4]) = *reinterpret_cast<const float4*>(&Ws[kk][tx * 8 + 4]);
            #pragma unroll
            for (int i = 0; i < 8; ++i)
                #pragma unroll
                for (int jx = 0; jx < 8; ++jx)
                    acc[i][jx] = fmaf(a[i], bb[jx], acc[i][jx]);
        }
        __syncthreads();
    }

    float bv[8];
    *reinterpret_cast<float4*>(&bv[0]) = *reinterpret_cast<const float4*>(&by[tx * 8]);
    *reinterpret_cast<float4*>(&bv[4]) = *reinterpret_cast<const float4*>(&by[tx * 8 + 4]);

    #pragma unroll
    for (int i = 0; i < 8; ++i) {
        float l[8];
        float mx = -1e30f;
        #pragma unroll
        for (int jx = 0; jx < 8; ++jx) { l[jx] = acc[i][jx] + bv[jx]; mx = fmaxf(mx, l[jx]); }
        mx = fmaxf(mx, __shfl_xor(mx, 16));
        mx = fmaxf(mx, __shfl_xor(mx, 8));
        mx = fmaxf(mx, __shfl_xor(mx, 4));
        mx = fmaxf(mx, __shfl_xor(mx, 2));
        mx = fmaxf(mx, __shfl_xor(mx, 1));
        float s = 0.f;
        #pragma unroll
        for (int jx = 0; jx < 8; ++jx) { float e = __expf(l[jx] - mx); l[jx] = e; s += e; }
        s += __shfl_xor(s, 16);
        s += __shfl_xor(s, 8);
        s += __shfl_xor(s, 4);
        s += __shfl_xor(s, 2);
        s += __shfl_xor(s, 1);
        float inv = 1.0f / s;
        #pragma unroll
        for (int jx = 0; jx < 8; ++jx) l[jx] *= inv;
        int m = m0 + ty * 8 + i;
        *reinterpret_cast<float4*>(&out[(size_t)m * O_ + tx * 8])     = *reinterpret_cast<float4*>(&l[0]);
        *reinterpret_cast<float4*>(&out[(size_t)m * O_ + tx * 8 + 4]) = *reinterpret_cast<float4*>(&l[4]);
    }
}

// ----------------------------------------------------------------
extern "C" void kernel_launch(void* const* d_in, const int* in_sizes, int n_in,
                              void* d_out, int out_size, void* d_ws, size_t ws_size,
                              hipStream_t stream) {
    const float* x   = (const float*)d_in[0];   // [B,T,I]
    const float* h0  = (const float*)d_in[1];   // [B,H]
    const float* Wxh = (const float*)d_in[2];   // [I,H]
    const float* Whh = (const float*)d_in[3];   // [H,H]
    const float* bh  = (const float*)d_in[4];   // [H]
    const float* Why = (const float*)d_in[5];   // [H,O]
    const float* byv = (const float*)d_in[6];   // [O]
    float* out = (float*)d_out;

    const size_t HA_BYTES   = (size_t)B_ * T_ * H_ * sizeof(float);          // 128 MB
    const size_t WP_BYTES   = (size_t)64 * H_ * sizeof(uint4);               // 512 KB
    const size_t PART_BYTES = (size_t)2 * S_ * B_ * H_ * sizeof(float);      // 1 MB
    const size_t CNT_BYTES  = (size_t)B_ * 16 * sizeof(int);                 // 4 KB
    if (ws_size < HA_BYTES + WP_BYTES + PART_BYTES + CNT_BYTES) return;

    float* HA   = (float*)d_ws;
    uint4* Wp   = (uint4*)((char*)d_ws + HA_BYTES);
    float* part = (float*)((char*)d_ws + HA_BYTES + WP_BYTES);
    int*   cnt  = (int*)((char*)d_ws + HA_BYTES + WP_BYTES + PART_BYTES);

    // counters must start at 0 every call (ws is re-poisoned 0xAA)
    hipMemsetAsync(cnt, 0, CNT_BYTES, stream);

    k_pack_whh<<<128, 256, 0, stream>>>(Whh, Wp);
    k_xw<<<dim3(H_ / 64, (B_ * T_) / 64), 256, 0, stream>>>(x, Wxh, bh, HA);

    float* hT = out + (size_t)B_ * T_ * O_;
    k_rnn<<<S_ * B_, 512, 0, stream>>>(Wp, HA, h0, hT, part, cnt);

    k_out<<<(B_ * T_) / 64, 256, 0, stream>>>(HA, Why, byv, out);
}

// Round 8
// 2756.244 us; speedup vs baseline: 6.7228x; 6.7228x over previous
//
#include <hip/hip_runtime.h>
#include <hip/hip_bf16.h>
#include <hip/hip_fp16.h>

#define B_ 64
#define T_ 1024
#define I_ 256
#define H_ 512
#define O_ 256

// ---------------------------------------------------------------- K0: pack W_hh -> int8, per-column scale
// chunk c = q*512 + j holds W[16q .. 16q+15][j] as 16 int8 (16B). q = k/16.
// wscale[j] = colmax|W[:,j]| / 127.
__global__ __launch_bounds__(128) void k_pack_whh_i8(const float* __restrict__ whh,
                                                     char* __restrict__ wq,
                                                     float* __restrict__ wscale) {
    const int j = blockIdx.x;            // column 0..511
    const int tid = threadIdx.x;         // 0..127
    float v[4];
    float m = 0.f;
    #pragma unroll
    for (int u = 0; u < 4; ++u) {
        v[u] = whh[(size_t)(tid + u * 128) * H_ + j];
        m = fmaxf(m, fabsf(v[u]));
    }
    #pragma unroll
    for (int off = 32; off >= 1; off >>= 1) m = fmaxf(m, __shfl_xor(m, off));
    __shared__ float wm[2];
    if ((tid & 63) == 0) wm[tid >> 6] = m;
    __syncthreads();
    m = fmaxf(fmaxf(wm[0], wm[1]), 1e-20f);
    if (tid == 0) wscale[j] = m / 127.f;
    const float inv = 127.f / m;
    #pragma unroll
    for (int u = 0; u < 4; ++u) {
        int k = tid + u * 128;
        wq[(((size_t)((k >> 4) * H_ + j)) << 4) + (k & 15)] = (char)(int)rintf(v[u] * inv);
    }
}

// ---------------------------------------------------------------- K1: xW = x @ W_xh + b_h   [65536,256]@[256,512]
__global__ __launch_bounds__(256) void k_xw(const float* __restrict__ A,
                                            const float* __restrict__ Bw,
                                            const float* __restrict__ bias,
                                            float* __restrict__ C) {
    __shared__ float As[16][64 + 4];
    __shared__ float Bs[16][64 + 4];
    const int tid = threadIdx.x;
    const int tx = tid & 15, ty = tid >> 4;
    const int bm = blockIdx.y * 64;
    const int bn = blockIdx.x * 64;
    float acc[4][4] = {};

    for (int k0 = 0; k0 < I_; k0 += 16) {
        {
            int r = tid >> 2, kq = (tid & 3) * 4;
            float4 v = *reinterpret_cast<const float4*>(&A[(size_t)(bm + r) * I_ + k0 + kq]);
            As[kq + 0][r] = v.x; As[kq + 1][r] = v.y; As[kq + 2][r] = v.z; As[kq + 3][r] = v.w;
        }
        {
            int kr = tid >> 4, nq = (tid & 15) * 4;
            float4 v = *reinterpret_cast<const float4*>(&Bw[(size_t)(k0 + kr) * H_ + bn + nq]);
            *reinterpret_cast<float4*>(&Bs[kr][nq]) = v;
        }
        __syncthreads();
        #pragma unroll
        for (int kk = 0; kk < 16; ++kk) {
            float a[4], b[4];
            *reinterpret_cast<float4*>(a) = *reinterpret_cast<const float4*>(&As[kk][ty * 4]);
            *reinterpret_cast<float4*>(b) = *reinterpret_cast<const float4*>(&Bs[kk][tx * 4]);
            #pragma unroll
            for (int i = 0; i < 4; ++i)
                #pragma unroll
                for (int jx = 0; jx < 4; ++jx)
                    acc[i][jx] = fmaf(a[i], b[jx], acc[i][jx]);
        }
        __syncthreads();
    }
    #pragma unroll
    for (int i = 0; i < 4; ++i) {
        int r = bm + ty * 4 + i;
        float4 o;
        o.x = acc[i][0] + bias[bn + tx * 4 + 0];
        o.y = acc[i][1] + bias[bn + tx * 4 + 1];
        o.z = acc[i][2] + bias[bn + tx * 4 + 2];
        o.w = acc[i][3] + bias[bn + tx * 4 + 3];
        *reinterpret_cast<float4*>(&C[(size_t)r * H_ + bn + tx * 4]) = o;
    }
}

// ---------------------------------------------------------------- K2: persistent recurrence, 1 block per batch row
// int8 W streamed from L2 (256 KB/step, half of fp16), int8 h in LDS, exact int32 dot via
// v_dot4_i32_i8. pre = xw + dot_i32 * (wscale[j]/127). h fp32 to HA for the output GEMM.
__global__ __launch_bounds__(512) void k_rnn(const uint4* __restrict__ Wq,      // [32][512] 16B chunks
                                             const float* __restrict__ wscale,  // [512]
                                             float* __restrict__ HA,            // [B,T,H] in: xw, out: h
                                             const float* __restrict__ h0,
                                             float* __restrict__ hT) {
    __shared__ __align__(16) char hbuf[2][H_];       // 1 KB
    const int b = blockIdx.x;
    const int j = threadIdx.x;                       // 0..511

    float h0v = h0[((size_t)b << 9) + j];
    hbuf[0][j] = (char)(int)rintf(fminf(fmaxf(h0v, -1.f), 1.f) * 127.f);
    __syncthreads();

    float* harow = HA + ((size_t)b << 19);           // b*T*H
    const uint4* wp = Wq + j;                        // chunk (q=0, col j); stride 512 per q
    const float ws = wscale[j] * (1.f / 127.f);
    int cur = 0;
    float hn = 0.f;

    for (int t = 0; t < T_; ++t) {
        float xw = harow[(t << 9) + j];              // independent: issue early
        const uint4* hb = reinterpret_cast<const uint4*>(&hbuf[cur][0]);
        int a0 = 0, a1 = 0, a2 = 0, a3 = 0;
        #pragma unroll 8
        for (int q = 0; q < 32; ++q) {
            uint4 w = wp[q << 9];                    // 16B coalesced, L2-resident stream
            uint4 h = hb[q];                         // 16 h-int8, wave-uniform broadcast
            a0 = __builtin_amdgcn_sdot4((int)w.x, (int)h.x, a0, false);
            a1 = __builtin_amdgcn_sdot4((int)w.y, (int)h.y, a1, false);
            a2 = __builtin_amdgcn_sdot4((int)w.z, (int)h.z, a2, false);
            a3 = __builtin_amdgcn_sdot4((int)w.w, (int)h.w, a3, false);
        }
        float pre = xw + (float)((a0 + a1) + (a2 + a3)) * ws;
        hn = tanhf(pre);
        harow[(t << 9) + j] = hn;                    // h_t for output GEMM (fp32)
        hbuf[cur ^ 1][j] = (char)(int)rintf(hn * 127.f);  // |hn|<1: no clamp needed
        __syncthreads();                             // single barrier per step
        cur ^= 1;
    }
    hT[((size_t)b << 9) + j] = hn;
}

// ---------------------------------------------------------------- K3: y = softmax(H @ W_hy + b_y)  fused
__global__ __launch_bounds__(256) void k_out(const float* __restrict__ Hh,   // [M,512]
                                             const float* __restrict__ Wy,   // [512,256]
                                             const float* __restrict__ by,   // [256]
                                             float* __restrict__ out) {      // [M,256]
    __shared__ float Hs[16][64 + 4];
    __shared__ float Ws[16][256];
    const int tid = threadIdx.x;
    const int tx = tid & 31, ty = tid >> 5;
    const int m0 = blockIdx.x * 64;
    float acc[8][8] = {};

    for (int k0 = 0; k0 < H_; k0 += 16) {
        {
            int r = tid >> 2, kq = (tid & 3) * 4;
            float4 v = *reinterpret_cast<const float4*>(&Hh[(size_t)(m0 + r) * H_ + k0 + kq]);
            Hs[kq + 0][r] = v.x; Hs[kq + 1][r] = v.y; Hs[kq + 2][r] = v.z; Hs[kq + 3][r] = v.w;
        }
        {
            int kr = tid >> 4, c0 = (tid & 15) * 16;
            const float4* src = reinterpret_cast<const float4*>(&Wy[(size_t)(k0 + kr) * O_ + c0]);
            float4* dst = reinterpret_cast<float4*>(&Ws[kr][c0]);
            dst[0] = src[0]; dst[1] = src[1]; dst[2] = src[2]; dst[3] = src[3];
        }
        __syncthreads();
        #pragma unroll
        for (int kk = 0; kk < 16; ++kk) {
            float a[8], bb[8];
            *reinterpret_cast<float4*>(&a[0])  = *reinterpret_cast<const float4*>(&Hs[kk][ty * 8]);
            *reinterpret_cast<float4*>(&a[4])  = *reinterpret_cast<const float4*>(&Hs[kk][ty * 8 + 4]);
            *reinterpret_cast<float4*>(&bb[0]) = *reinterpret_cast<const float4*>(&Ws[kk][tx * 8]);
            *reinterpret_cast<float4*>(&bb[4]) = *reinterpret_cast<const float4*>(&Ws[kk][tx * 8 + 4]);
            #pragma unroll
            for (int i = 0; i < 8; ++i)
                #pragma unroll
                for (int jx = 0; jx < 8; ++jx)
                    acc[i][jx] = fmaf(a[i], bb[jx], acc[i][jx]);
        }
        __syncthreads();
    }

    float bv[8];
    *reinterpret_cast<float4*>(&bv[0]) = *reinterpret_cast<const float4*>(&by[tx * 8]);
    *reinterpret_cast<float4*>(&bv[4]) = *reinterpret_cast<const float4*>(&by[tx * 8 + 4]);

    #pragma unroll
    for (int i = 0; i < 8; ++i) {
        float l[8];
        float mx = -1e30f;
        #pragma unroll
        for (int jx = 0; jx < 8; ++jx) { l[jx] = acc[i][jx] + bv[jx]; mx = fmaxf(mx, l[jx]); }
        mx = fmaxf(mx, __shfl_xor(mx, 16));
        mx = fmaxf(mx, __shfl_xor(mx, 8));
        mx = fmaxf(mx, __shfl_xor(mx, 4));
        mx = fmaxf(mx, __shfl_xor(mx, 2));
        mx = fmaxf(mx, __shfl_xor(mx, 1));
        float s = 0.f;
        #pragma unroll
        for (int jx = 0; jx < 8; ++jx) { float e = __expf(l[jx] - mx); l[jx] = e; s += e; }
        s += __shfl_xor(s, 16);
        s += __shfl_xor(s, 8);
        s += __shfl_xor(s, 4);
        s += __shfl_xor(s, 2);
        s += __shfl_xor(s, 1);
        float inv = 1.0f / s;
        #pragma unroll
        for (int jx = 0; jx < 8; ++jx) l[jx] *= inv;
        int m = m0 + ty * 8 + i;
        *reinterpret_cast<float4*>(&out[(size_t)m * O_ + tx * 8])     = *reinterpret_cast<float4*>(&l[0]);
        *reinterpret_cast<float4*>(&out[(size_t)m * O_ + tx * 8 + 4]) = *reinterpret_cast<float4*>(&l[4]);
    }
}

// ----------------------------------------------------------------
extern "C" void kernel_launch(void* const* d_in, const int* in_sizes, int n_in,
                              void* d_out, int out_size, void* d_ws, size_t ws_size,
                              hipStream_t stream) {
    const float* x   = (const float*)d_in[0];   // [B,T,I]
    const float* h0  = (const float*)d_in[1];   // [B,H]
    const float* Wxh = (const float*)d_in[2];   // [I,H]
    const float* Whh = (const float*)d_in[3];   // [H,H]
    const float* bh  = (const float*)d_in[4];   // [H]
    const float* Why = (const float*)d_in[5];   // [H,O]
    const float* byv = (const float*)d_in[6];   // [O]
    float* out = (float*)d_out;

    const size_t HA_BYTES = (size_t)B_ * T_ * H_ * sizeof(float);      // 128 MB
    const size_t WQ_BYTES = (size_t)H_ * H_;                           // 256 KB int8
    const size_t WS_BYTES = (size_t)H_ * sizeof(float);                // 2 KB scales
    if (ws_size < HA_BYTES + WQ_BYTES + WS_BYTES) return;

    float* HA     = (float*)d_ws;
    char*  Wq     = (char*)d_ws + HA_BYTES;
    float* wscale = (float*)((char*)d_ws + HA_BYTES + WQ_BYTES);

    // pack W_hh to int8 + per-column scales (runs every call; cheap)
    k_pack_whh_i8<<<H_, 128, 0, stream>>>(Whh, Wq, wscale);

    // xW = x @ W_xh + b_h  -> HA
    k_xw<<<dim3(H_ / 64, (B_ * T_) / 64), 256, 0, stream>>>(x, Wxh, bh, HA);

    // recurrence: 64 persistent blocks, h_t overwrites HA, h_T -> tail of d_out
    float* hT = out + (size_t)B_ * T_ * O_;
    k_rnn<<<B_, 512, 0, stream>>>((const uint4*)Wq, wscale, HA, h0, hT);

    // outputs = softmax(HA @ W_hy + b_y)
    k_out<<<(B_ * T_) / 64, 256, 0, stream>>>(HA, Why, byv, out);
}